// Round 1
// baseline (2602.453 us; speedup 1.0000x reference)
//
#include <hip/hip_runtime.h>

#define NB 64
#define NPTS 500
#define ND 2048
#define NK 10
#define NITERS 10
#define FEPS 1e-6f

// ---------------------------------------------------------------------------
// init: copy features[:, :NK, :] -> centroids ; zero per-iteration counts
// ---------------------------------------------------------------------------
__global__ __launch_bounds__(256) void init_kernel(const float* __restrict__ f,
                                                   float* __restrict__ cent,
                                                   int* __restrict__ counts)
{
    int gid = blockIdx.x * 256 + threadIdx.x;           // 160*256 = 40960 threads
    if (gid < NITERS * NB * NK) counts[gid] = 0;

    const int total4 = NB * NK * ND / 4;                // 327680 float4
    for (int i = gid; i < total4; i += gridDim.x * 256) {
        int d4 = i & (ND / 4 - 1);                      // ND/4 = 512 (pow2)
        int bk = i >> 9;
        int b = bk / NK, k = bk - b * NK;
        ((float4*)cent)[i] =
            ((const float4*)(f + ((size_t)b * NPTS + k) * ND))[d4];
    }
}

// ---------------------------------------------------------------------------
// assign: one wave handles 2 points. score = 0.5*||c||^2 - f.c  (same argmin
// as ||f||^2 - 2 f.c + ||c||^2). Strict < ascending scan == jnp.argmin
// first-occurrence tie-break.
// ---------------------------------------------------------------------------
__global__ __launch_bounds__(256) void assign_kernel(const float* __restrict__ f,
                                                     const float* __restrict__ cent,
                                                     int* __restrict__ assign,
                                                     int* __restrict__ counts_it)
{
    const int b    = blockIdx.y;
    const int wv   = threadIdx.x >> 6;
    const int lane = threadIdx.x & 63;
    const int n0   = blockIdx.x * 8 + wv * 2;
    const int n1   = n0 + 1;
    const bool v0  = (n0 < NPTS), v1 = (n1 < NPTS);

    const float4* f4 = (const float4*)(f + (size_t)b * NPTS * ND);
    const float4  z4 = make_float4(0.f, 0.f, 0.f, 0.f);
    float4 fa[8], fb[8];
#pragma unroll
    for (int j = 0; j < 8; ++j) {
        int idx = j * 64 + lane;                        // 512 float4 per row
        fa[j] = v0 ? f4[(size_t)n0 * 512 + idx] : z4;
        fb[j] = v1 ? f4[(size_t)n1 * 512 + idx] : z4;
    }

    const float4* c4 = (const float4*)(cent + (size_t)b * NK * ND);
    float sA[NK], sB[NK];
#pragma unroll
    for (int k = 0; k < NK; ++k) {
        float a0 = 0.f, a1 = 0.f, c2 = 0.f;
#pragma unroll
        for (int j = 0; j < 8; ++j) {
            float4 c = c4[k * 512 + j * 64 + lane];
            a0 = fmaf(fa[j].x, c.x, a0); a0 = fmaf(fa[j].y, c.y, a0);
            a0 = fmaf(fa[j].z, c.z, a0); a0 = fmaf(fa[j].w, c.w, a0);
            a1 = fmaf(fb[j].x, c.x, a1); a1 = fmaf(fb[j].y, c.y, a1);
            a1 = fmaf(fb[j].z, c.z, a1); a1 = fmaf(fb[j].w, c.w, a1);
            c2 = fmaf(c.x, c.x, c2);     c2 = fmaf(c.y, c.y, c2);
            c2 = fmaf(c.z, c.z, c2);     c2 = fmaf(c.w, c.w, c2);
        }
#pragma unroll
        for (int off = 32; off > 0; off >>= 1) {
            a0 += __shfl_xor(a0, off, 64);
            a1 += __shfl_xor(a1, off, 64);
            c2 += __shfl_xor(c2, off, 64);
        }
        sA[k] = 0.5f * c2 - a0;                          // *0.5 exact (pow2)
        sB[k] = 0.5f * c2 - a1;
    }

    int i0 = 0, i1 = 0;
    float b0 = sA[0], b1 = sB[0];
#pragma unroll
    for (int k = 1; k < NK; ++k) {
        if (sA[k] < b0) { b0 = sA[k]; i0 = k; }
        if (sB[k] < b1) { b1 = sB[k]; i1 = k; }
    }
    if (lane == 0) {
        if (v0) { assign[b * NPTS + n0] = i0; atomicAdd(&counts_it[b * NK + i0], 1); }
        if (v1) { assign[b * NPTS + n1] = i1; atomicAdd(&counts_it[b * NK + i1], 1); }
    }
}

// ---------------------------------------------------------------------------
// update: thread per (b, d). Loops all 500 points; assigns staged in LDS.
// acc[] fully unrolled -> static register indexing (no scratch).
// Empty cluster => acc 0 / max(cnt,1)=1 => centroid becomes 0 (matches ref).
// ---------------------------------------------------------------------------
__global__ __launch_bounds__(256) void update_kernel(const float* __restrict__ f,
                                                     const int* __restrict__ assign,
                                                     const int* __restrict__ counts_it,
                                                     float* __restrict__ cent)
{
    __shared__ int sAsn[NPTS];
    const int b = blockIdx.y;
    const int d = blockIdx.x * 256 + threadIdx.x;
    for (int i = threadIdx.x; i < NPTS; i += 256) sAsn[i] = assign[b * NPTS + i];
    __syncthreads();

    float acc[NK];
#pragma unroll
    for (int k = 0; k < NK; ++k) acc[k] = 0.f;

    const float* fp = f + (size_t)b * NPTS * ND + d;
#pragma unroll 4
    for (int n = 0; n < NPTS; ++n) {
        float v = fp[(size_t)n * ND];
        int a = sAsn[n];
#pragma unroll
        for (int k = 0; k < NK; ++k) acc[k] += (a == k) ? v : 0.f;
    }

    float* cp = cent + (size_t)b * NK * ND + d;
#pragma unroll
    for (int k = 0; k < NK; ++k) {
        float cnt = (float)counts_it[b * NK + k];
        cp[(size_t)k * ND] = acc[k] / fmaxf(cnt, 1.f);
    }
}

// ---------------------------------------------------------------------------
// gem: final pass. powed = clip(f,eps)^p accumulated per cluster; out =
// counts>0 ? (mean)^(1/p) : final centroid.
// ---------------------------------------------------------------------------
__global__ __launch_bounds__(256) void gem_kernel(const float* __restrict__ f,
                                                  const float* __restrict__ p_ptr,
                                                  const int* __restrict__ assign,
                                                  const int* __restrict__ counts_it,
                                                  const float* __restrict__ cent,
                                                  float* __restrict__ out)
{
    __shared__ int sAsn[NPTS];
    const int b = blockIdx.y;
    const int d = blockIdx.x * 256 + threadIdx.x;
    const float p = p_ptr[0];
    for (int i = threadIdx.x; i < NPTS; i += 256) sAsn[i] = assign[b * NPTS + i];
    __syncthreads();

    float acc[NK];
#pragma unroll
    for (int k = 0; k < NK; ++k) acc[k] = 0.f;

    const float* fp = f + (size_t)b * NPTS * ND + d;
#pragma unroll 2
    for (int n = 0; n < NPTS; ++n) {
        float v  = fp[(size_t)n * ND];
        float x  = fmaxf(v, FEPS);
        float pw = __expf(p * __logf(x));               // x >= eps > 0
        int a = sAsn[n];
#pragma unroll
        for (int k = 0; k < NK; ++k) acc[k] += (a == k) ? pw : 0.f;
    }

    const float invp = 1.f / p;
#pragma unroll
    for (int k = 0; k < NK; ++k) {
        int cnt = counts_it[b * NK + k];
        float res;
        if (cnt > 0) {
            float mean = acc[k] / (float)cnt;            // cnt>0 => max(cnt,1)=cnt
            res = __expf(invp * __logf(mean));
        } else {
            res = cent[((size_t)b * NK + k) * ND + d];
        }
        out[((size_t)b * NK + k) * ND + d] = res;
    }
}

// ---------------------------------------------------------------------------
extern "C" void kernel_launch(void* const* d_in, const int* in_sizes, int n_in,
                              void* d_out, int out_size, void* d_ws, size_t ws_size,
                              hipStream_t stream)
{
    (void)in_sizes; (void)n_in; (void)out_size; (void)ws_size;

    const float* f = (const float*)d_in[0];
    const float* p = (const float*)d_in[1];
    float* out = (float*)d_out;

    float* cent   = (float*)d_ws;                        // NB*NK*ND   (5.24 MB)
    int*   assign = (int*)(cent + (size_t)NB * NK * ND); // NB*NPTS    (128 KB)
    int*   counts = assign + NB * NPTS;                  // NITERS*NB*NK (25.6 KB)

    init_kernel<<<160, 256, 0, stream>>>(f, cent, counts);
    for (int it = 0; it < NITERS; ++it) {
        assign_kernel<<<dim3(63, NB), 256, 0, stream>>>(f, cent, assign,
                                                        counts + it * NB * NK);
        update_kernel<<<dim3(ND / 256, NB), 256, 0, stream>>>(f, assign,
                                                              counts + it * NB * NK, cent);
    }
    gem_kernel<<<dim3(ND / 256, NB), 256, 0, stream>>>(f, p, assign,
                                                       counts + (NITERS - 1) * NB * NK,
                                                       cent, out);
}